// Round 5
// baseline (810.767 us; speedup 1.0000x reference)
//
#include <hip/hip_runtime.h>
#include <stdint.h>

#define BATCH 256
#define NNODE 512
#define INP   57
#define HIDD  512
#define OUTD  57

typedef __bf16 bf16x8 __attribute__((ext_vector_type(8)));
typedef float  f32x4  __attribute__((ext_vector_type(4)));

__device__ __forceinline__ float bf2f(unsigned short u){
  union { unsigned int i; float f; } c; c.i = ((unsigned int)u) << 16; return c.f;
}
__device__ __forceinline__ unsigned short f2bf(float f){
  union { float f; unsigned int i; } c; c.f = f;
  unsigned int u = c.i;
  return (unsigned short)((u + 0x7fffu + ((u >> 16) & 1u)) >> 16);
}

// Pre-pack Wh = W_ih[INP:, :] into MFMA B-fragment order (bf16).
// Fragment id = kt*32 + ntile; lane holds B[k=kt*32+(lane>>4)*8+j][n=ntile*16+(lane&15)], j=0..7.
__global__ void pack_wh(const float* __restrict__ W_ih, unsigned short* __restrict__ Wp){
  int idx = blockIdx.x * 256 + threadIdx.x;      // 0..262143
  int j    =  idx        & 7;
  int lane = (idx >> 3)  & 63;
  int nt   = (idx >> 9)  & 31;
  int kt   =  idx >> 14;                         // 0..15
  int k = kt * 32 + (lane >> 4) * 8 + j;
  int n = nt * 16 + (lane & 15);
  Wp[idx] = f2bf(W_ih[(size_t)(INP + k) * HIDD + n]);
}

// One pass: up to 8*MT nodes of one level. A rows = child rows (2 per node),
// gathered DIRECTLY into registers (no LDS staging, no gather barrier):
// lane (m16,quad) of m-tile mt reads H[src(mt,m16)][kt*32 + quad*8 .. +8] — a
// contiguous 16B chunk; a wave reads 16 rows x 64B contiguous per kt.
// D = A@Wh gives h_l@Wh and h_r@Wh in adjacent acc regs; epilogue adds them.
// ALL register arrays statically indexed (spill discipline).
template<int MT>
__device__ __forceinline__ void do_pass(
    const int* __restrict__ ord_s, const int* __restrict__ li_s,
    const int* __restrict__ ri_s,  const int* __restrict__ val_s,
    int m0, int nodes,
    unsigned short* __restrict__ Hb,
    const unsigned short* __restrict__ Wq,
    const float* __restrict__ W_ih, const float* bias,
    int w, int lane, int m16, int quad)
{
  // per-lane A row base pointers (element offset quad*8 folded in; per-kt imm = kt*32 elems)
  const unsigned short* aptr[MT];
  #pragma unroll
  for (int mt = 0; mt < MT; ++mt) {
    const int r  = mt * 16 + m16;
    const int nl = r >> 1;
    int src = NNODE;
    if (nl < nodes) {
      const int node = ord_s[m0 + nl];
      const int c = (r & 1) ? ri_s[node] : li_s[node];
      src = (c < 0) ? NNODE : c;
    }
    aptr[mt] = Hb + (size_t)src * HIDD + quad * 8;
  }

  // depth-2 ping-pong preload: kt = 0,1 for both A and B
  bf16x8 A2[2][MT], B2[2][4];
  #pragma unroll
  for (int mt = 0; mt < MT; ++mt) {
    A2[0][mt] = *(const bf16x8*)(aptr[mt]);
    A2[1][mt] = *(const bf16x8*)(aptr[mt] + 32);
  }
  #pragma unroll
  for (int nt = 0; nt < 4; ++nt) {
    B2[0][nt] = *(const bf16x8*)(Wq + (size_t)(0 * 32 + nt) * 512);
    B2[1][nt] = *(const bf16x8*)(Wq + (size_t)(1 * 32 + nt) * 512);
  }

  // xp prefetch: W_ih[val[node]][col] (in flight during kt loop, used in epilogue)
  float xp[MT][2][4];
  #pragma unroll
  for (int mt = 0; mt < MT; ++mt) {
    #pragma unroll
    for (int p = 0; p < 2; ++p) {
      const int nl = mt * 8 + quad * 2 + p;
      if (nl < nodes) {
        const float* wr = W_ih + (size_t)val_s[ord_s[m0 + nl]] * HIDD;
        #pragma unroll
        for (int nt = 0; nt < 4; ++nt) xp[mt][p][nt] = wr[(w * 4 + nt) * 16 + m16];
      } else {
        #pragma unroll
        for (int nt = 0; nt < 4; ++nt) xp[mt][p][nt] = 0.f;
      }
    }
  }

  f32x4 acc[MT][4];
  #pragma unroll
  for (int mt = 0; mt < MT; ++mt)
    #pragma unroll
    for (int nt = 0; nt < 4; ++nt) acc[mt][nt] = (f32x4){0.f,0.f,0.f,0.f};

  #pragma unroll
  for (int kt = 0; kt < 16; ++kt) {
    bf16x8 a[MT], bb[4];
    #pragma unroll
    for (int mt = 0; mt < MT; ++mt) a[mt] = A2[kt & 1][mt];
    #pragma unroll
    for (int nt = 0; nt < 4; ++nt)  bb[nt] = B2[kt & 1][nt];
    if (kt < 14) {   // issue prefetch for kt+2 before the MFMAs
      #pragma unroll
      for (int mt = 0; mt < MT; ++mt)
        A2[kt & 1][mt] = *(const bf16x8*)(aptr[mt] + (kt + 2) * 32);
      #pragma unroll
      for (int nt = 0; nt < 4; ++nt)
        B2[kt & 1][nt] = *(const bf16x8*)(Wq + (size_t)((kt + 2) * 32 + nt) * 512);
    }
    #pragma unroll
    for (int nt = 0; nt < 4; ++nt)
      #pragma unroll
      for (int mt = 0; mt < MT; ++mt)
        acc[mt][nt] = __builtin_amdgcn_mfma_f32_16x16x32_bf16(a[mt], bb[nt], acc[mt][nt], 0, 0, 0);
  }

  // epilogue: h = tanh(accL + accR + xp + bias) -> H[b][node][:] (bf16)
  // C/D: col = lane&15, row = quad*4 + reg. Rows (2n,2n+1) are regs (2p,2p+1).
  #pragma unroll
  for (int mt = 0; mt < MT; ++mt) {
    #pragma unroll
    for (int p = 0; p < 2; ++p) {
      const int nl = mt * 8 + quad * 2 + p;
      if (nl < nodes) {
        const int node = ord_s[m0 + nl];
        #pragma unroll
        for (int nt = 0; nt < 4; ++nt) {
          const int col = (w * 4 + nt) * 16 + m16;
          const float v = acc[mt][nt][2 * p] + acc[mt][nt][2 * p + 1] + xp[mt][p][nt] + bias[nt];
          const float e = __expf(2.0f * v);
          const float t = 1.0f - __fdividef(2.0f, e + 1.0f);
          Hb[(size_t)node * HIDD + col] = f2bf(t);
        }
      }
    }
  }
  __syncthreads();   // stores drained (vmcnt(0)) + visible before next pass's gathers
}

__global__ __launch_bounds__(512, 2) void tree_rnn(
    const int* __restrict__ left, const int* __restrict__ right,
    const int* __restrict__ values,
    const float* __restrict__ W_ih, const float* __restrict__ b_ih,
    const float* __restrict__ W_o,  const float* __restrict__ b_o,
    const unsigned short* __restrict__ Wp,
    unsigned short* __restrict__ Hbuf, float* __restrict__ out)
{
  __shared__ int li_s[NNODE], ri_s[NNODE], val_s[NNODE];
  __shared__ int lvl_s[NNODE], ord_s[NNODE];
  __shared__ int cnt_s[NNODE], cnt2_s[NNODE];
  __shared__ int offs_s[NNODE + 1];
  __shared__ int chg_s, lmax_s;
  __shared__ float hroot_s[HIDD];
  __shared__ float red_s[OUTD][8];
  __shared__ float logit_s[64];

  const int b    = blockIdx.x;
  const int tid  = threadIdx.x;
  const int lane = tid & 63;
  const int w    = tid >> 6;
  unsigned short* Hb = Hbuf + (size_t)b * (NNODE + 1) * HIDD;

  // ---- load tree + init (zero the sentinel row: ws is poisoned 0xAA) ----
  li_s[tid]  = left  [b * NNODE + tid];
  ri_s[tid]  = right [b * NNODE + tid];
  val_s[tid] = values[b * NNODE + tid];
  lvl_s[tid] = 0; cnt_s[tid] = 0; cnt2_s[tid] = 0;
  Hb[(size_t)NNODE * HIDD + tid] = 0;
  if (tid == 0) lmax_s = 0;
  __syncthreads();

  // ---- level fixpoint: lvl[i] = 1 + max(lvl[children]), null -> -1 ----
  for (;;) {
    if (tid == 0) chg_s = 0;
    __syncthreads();
    int l = li_s[tid], r = ri_s[tid];
    int dl = (l >= 0) ? lvl_s[l] : -1;
    int dr = (r >= 0) ? lvl_s[r] : -1;
    int nl = 1 + (dl > dr ? dl : dr);
    if (nl > lvl_s[tid]) { lvl_s[tid] = nl; chg_s = 1; }
    __syncthreads();
    if (!chg_s) break;
  }

  // ---- bucket by level (counting sort in LDS) ----
  const int myl = lvl_s[tid];
  int ml = myl;
  #pragma unroll
  for (int m = 1; m < 64; m <<= 1) ml = max(ml, __shfl_xor(ml, m, 64));
  if (lane == 0) atomicMax(&lmax_s, ml);
  atomicAdd(&cnt_s[myl], 1);
  __syncthreads();
  const int Lmax = lmax_s;
  if (tid == 0) {
    int acc = 0;
    for (int L = 0; L <= Lmax; ++L) { offs_s[L] = acc; acc += cnt_s[L]; }
    offs_s[Lmax + 1] = acc;
  }
  __syncthreads();
  {
    int pos = offs_s[myl] + atomicAdd(&cnt2_s[myl], 1);
    ord_s[pos] = tid;
  }
  __syncthreads();

  const int m16  = lane & 15;
  const int quad = lane >> 4;
  const unsigned short* Wq = Wp + (size_t)(w * 4) * 512 + (size_t)lane * 8;

  float bias[4];
  #pragma unroll
  for (int nt = 0; nt < 4; ++nt) bias[nt] = b_ih[(w * 4 + nt) * 16 + m16];

  // ---- level loop ----
  for (int L = 0; L <= Lmax; ++L) {
    const int start = offs_s[L], end = offs_s[L + 1];
    for (int m0 = start; m0 < end; m0 += 32) {
      const int nodes = min(32, end - m0);
      if (nodes <= 8)
        do_pass<1>(ord_s, li_s, ri_s, val_s, m0, nodes, Hb, Wq, W_ih, bias, w, lane, m16, quad);
      else if (nodes <= 16)
        do_pass<2>(ord_s, li_s, ri_s, val_s, m0, nodes, Hb, Wq, W_ih, bias, w, lane, m16, quad);
      else
        do_pass<4>(ord_s, li_s, ri_s, val_s, m0, nodes, Hb, Wq, W_ih, bias, w, lane, m16, quad);
    }
  }

  // ---- logits + log_softmax ----
  hroot_s[tid] = bf2f(Hb[(size_t)(NNODE - 1) * HIDD + tid]);
  __syncthreads();
  {
    const int j = tid >> 3, part = tid & 7;
    if (j < OUTD) {
      float p = 0.f;
      const int k0 = part * 64;
      for (int k = k0; k < k0 + 64; ++k)
        p += hroot_s[k] * W_o[(size_t)k * OUTD + j];
      red_s[j][part] = p;
    }
  }
  __syncthreads();
  if (tid < OUTD) {
    float s = b_o[tid];
    #pragma unroll
    for (int p = 0; p < 8; ++p) s += red_s[tid][p];
    logit_s[tid] = s;
  }
  __syncthreads();
  if (w == 0) {
    float x = (lane < OUTD) ? logit_s[lane] : -1e30f;
    float mx = x;
    #pragma unroll
    for (int m = 1; m < 64; m <<= 1) mx = fmaxf(mx, __shfl_xor(mx, m, 64));
    float ex = (lane < OUTD) ? __expf(x - mx) : 0.f;
    float sm = ex;
    #pragma unroll
    for (int m = 1; m < 64; m <<= 1) sm += __shfl_xor(sm, m, 64);
    float ls = logf(sm);
    if (lane < OUTD) out[b * OUTD + lane] = x - mx - ls;
  }
}

extern "C" void kernel_launch(void* const* d_in, const int* in_sizes, int n_in,
                              void* d_out, int out_size, void* d_ws, size_t ws_size,
                              hipStream_t stream) {
  const int*   left   = (const int*)  d_in[0];
  const int*   right  = (const int*)  d_in[1];
  const int*   values = (const int*)  d_in[2];
  const float* W_ih   = (const float*)d_in[3];
  const float* b_ih   = (const float*)d_in[4];
  const float* W_o    = (const float*)d_in[5];
  const float* b_o    = (const float*)d_in[6];
  float* out = (float*)d_out;

  unsigned short* Wp   = (unsigned short*)d_ws;
  unsigned short* Hbuf = (unsigned short*)((char*)d_ws + 512 * 1024);

  pack_wh<<<1024, 256, 0, stream>>>(W_ih, Wp);
  tree_rnn<<<BATCH, 512, 0, stream>>>(left, right, values, W_ih, b_ih, W_o, b_o,
                                      Wp, Hbuf, out);
}

// Round 6
// 577.704 us; speedup vs baseline: 1.4034x; 1.4034x over previous
//
#include <hip/hip_runtime.h>
#include <stdint.h>

#define BATCH 256
#define NNODE 512
#define INP   57
#define HIDD  512
#define OUTD  57
#define AST   520   // A_s row stride in shorts: 260 dwords ≡ 4 (mod 32) -> minimal bank conflicts

typedef __bf16 bf16x8 __attribute__((ext_vector_type(8)));
typedef float  f32x4  __attribute__((ext_vector_type(4)));

__device__ __forceinline__ float bf2f(unsigned short u){
  union { unsigned int i; float f; } c; c.i = ((unsigned int)u) << 16; return c.f;
}
__device__ __forceinline__ unsigned short f2bf(float f){
  union { float f; unsigned int i; } c; c.f = f;
  unsigned int u = c.i;
  return (unsigned short)((u + 0x7fffu + ((u >> 16) & 1u)) >> 16);
}

// Pre-pack Wh = W_ih[INP:, :] into MFMA B-fragment order (bf16).
// Fragment id = kt*32 + ntile; lane holds B[k=kt*32+(lane>>4)*8+j][n=ntile*16+(lane&15)], j=0..7.
__global__ void pack_wh(const float* __restrict__ W_ih, unsigned short* __restrict__ Wp){
  int idx = blockIdx.x * 256 + threadIdx.x;      // 0..262143
  int j    =  idx        & 7;
  int lane = (idx >> 3)  & 63;
  int nt   = (idx >> 9)  & 31;
  int kt   =  idx >> 14;                         // 0..15
  int k = kt * 32 + (lane >> 4) * 8 + j;
  int n = nt * 16 + (lane & 15);
  Wp[idx] = f2bf(W_ih[(size_t)(INP + k) * HIDD + n]);
}

// One pass: up to 8*MT nodes of one level. A rows = RAW child rows (2/node),
// COPIED cooperatively into LDS (8 lanes per row, contiguous 128B chunks —
// the r1 cache-friendly pattern, zero repack VALU). The hl+hr add happens in
// the f32 epilogue (acc regs 2p/2p+1). All register indices compile-time.
template<int MT>
__device__ __forceinline__ void do_pass(
    unsigned short* __restrict__ A_s,
    const int* __restrict__ ord_s, const int* __restrict__ li_s,
    const int* __restrict__ ri_s,  const int* __restrict__ val_s,
    int m0, int nodes,
    unsigned short* __restrict__ Hb,
    const unsigned short* __restrict__ Wq,
    const float* __restrict__ W_ih, const float* bias,
    int tid, int w, int lane, int m16, int quad)
{
  // ---- cooperative copy-gather: rows = 16*MT, 8 threads/row ----
  if (tid < MT * 16 * 8) {
    const int r  = tid >> 3;                     // A row
    const int cp = tid & 7;
    const int nl = r >> 1;
    int src = NNODE;                             // sentinel (zeros) for pads/null
    if (nl < nodes) {
      const int node = ord_s[m0 + nl];
      const int c = (r & 1) ? ri_s[node] : li_s[node];
      src = (c < 0) ? NNODE : c;
    }
    const unsigned short* gp = Hb + (size_t)src * HIDD + cp * 8;
    unsigned short*       lp = A_s + r * AST + cp * 8;
    #pragma unroll
    for (int it = 0; it < 8; ++it)
      *(uint4*)(lp + it * 64) = *(const uint4*)(gp + it * 64);
  }

  // preload B fragments kt=0,1 (in flight across the barrier)
  bf16x8 B2[2][4];
  #pragma unroll
  for (int nt = 0; nt < 4; ++nt) {
    B2[0][nt] = *(const bf16x8*)(Wq + (size_t)(0 * 32 + nt) * 512);
    B2[1][nt] = *(const bf16x8*)(Wq + (size_t)(1 * 32 + nt) * 512);
  }

  __syncthreads();

  // xp prefetch: W_ih[val[node]][col] (in flight under kt loop)
  float xp[MT][2][4];
  #pragma unroll
  for (int mt = 0; mt < MT; ++mt) {
    #pragma unroll
    for (int p = 0; p < 2; ++p) {
      const int nl = mt * 8 + quad * 2 + p;
      if (nl < nodes) {
        const float* wr = W_ih + (size_t)val_s[ord_s[m0 + nl]] * HIDD;
        #pragma unroll
        for (int nt = 0; nt < 4; ++nt) xp[mt][p][nt] = wr[(w * 4 + nt) * 16 + m16];
      } else {
        #pragma unroll
        for (int nt = 0; nt < 4; ++nt) xp[mt][p][nt] = 0.f;
      }
    }
  }

  f32x4 acc[MT][4];
  #pragma unroll
  for (int mt = 0; mt < MT; ++mt)
    #pragma unroll
    for (int nt = 0; nt < 4; ++nt) acc[mt][nt] = (f32x4){0.f,0.f,0.f,0.f};

  #pragma unroll
  for (int kt = 0; kt < 16; ++kt) {
    bf16x8 a[MT], bb[4];
    #pragma unroll
    for (int mt = 0; mt < MT; ++mt)
      a[mt] = *(const bf16x8*)&A_s[(mt * 16 + m16) * AST + kt * 32 + quad * 8];
    #pragma unroll
    for (int nt = 0; nt < 4; ++nt) bb[nt] = B2[kt & 1][nt];
    if (kt < 14) {
      #pragma unroll
      for (int nt = 0; nt < 4; ++nt)
        B2[kt & 1][nt] = *(const bf16x8*)(Wq + (size_t)((kt + 2) * 32 + nt) * 512);
    }
    #pragma unroll
    for (int nt = 0; nt < 4; ++nt)
      #pragma unroll
      for (int mt = 0; mt < MT; ++mt)
        acc[mt][nt] = __builtin_amdgcn_mfma_f32_16x16x32_bf16(a[mt], bb[nt], acc[mt][nt], 0, 0, 0);
  }

  // epilogue: h = tanh(accL + accR + xp + bias) -> H[b][node][:] (bf16)
  // C/D: col = lane&15, row = quad*4 + reg; A rows (2n,2n+1) -> regs (2p,2p+1)
  #pragma unroll
  for (int mt = 0; mt < MT; ++mt) {
    #pragma unroll
    for (int p = 0; p < 2; ++p) {
      const int nl = mt * 8 + quad * 2 + p;
      if (nl < nodes) {
        const int node = ord_s[m0 + nl];
        #pragma unroll
        for (int nt = 0; nt < 4; ++nt) {
          const int col = (w * 4 + nt) * 16 + m16;
          const float v = acc[mt][nt][2 * p] + acc[mt][nt][2 * p + 1] + xp[mt][p][nt] + bias[nt];
          const float e = __expf(2.0f * v);
          const float t = 1.0f - __fdividef(2.0f, e + 1.0f);
          Hb[(size_t)node * HIDD + col] = f2bf(t);
        }
      }
    }
  }
  __syncthreads();   // stores drained + visible before next pass's gather
}

__global__ __launch_bounds__(512, 2) void tree_rnn(
    const int* __restrict__ left, const int* __restrict__ right,
    const int* __restrict__ values,
    const float* __restrict__ W_ih, const float* __restrict__ b_ih,
    const float* __restrict__ W_o,  const float* __restrict__ b_o,
    const unsigned short* __restrict__ Wp,
    unsigned short* __restrict__ Hbuf, float* __restrict__ out)
{
  __shared__ unsigned short A_s[64 * AST];       // 66560 B
  __shared__ int li_s[NNODE], ri_s[NNODE], val_s[NNODE];
  __shared__ int lvl_s[NNODE], ord_s[NNODE];
  __shared__ int cnt_s[NNODE], cnt2_s[NNODE];
  __shared__ int offs_s[NNODE + 1];
  __shared__ int chg_s, lmax_s;
  __shared__ float hroot_s[HIDD];
  __shared__ float red_s[OUTD][8];
  __shared__ float logit_s[64];

  const int b    = blockIdx.x;
  const int tid  = threadIdx.x;
  const int lane = tid & 63;
  const int w    = tid >> 6;
  unsigned short* Hb = Hbuf + (size_t)b * (NNODE + 1) * HIDD;

  // ---- load tree + init (zero the sentinel row: ws is poisoned 0xAA) ----
  li_s[tid]  = left  [b * NNODE + tid];
  ri_s[tid]  = right [b * NNODE + tid];
  val_s[tid] = values[b * NNODE + tid];
  lvl_s[tid] = 0; cnt_s[tid] = 0; cnt2_s[tid] = 0;
  Hb[(size_t)NNODE * HIDD + tid] = 0;
  if (tid == 0) lmax_s = 0;
  __syncthreads();

  // ---- level fixpoint: lvl[i] = 1 + max(lvl[children]), null -> -1 ----
  for (;;) {
    if (tid == 0) chg_s = 0;
    __syncthreads();
    int l = li_s[tid], r = ri_s[tid];
    int dl = (l >= 0) ? lvl_s[l] : -1;
    int dr = (r >= 0) ? lvl_s[r] : -1;
    int nl = 1 + (dl > dr ? dl : dr);
    if (nl > lvl_s[tid]) { lvl_s[tid] = nl; chg_s = 1; }
    __syncthreads();
    if (!chg_s) break;
  }

  // ---- bucket by level (counting sort in LDS) ----
  const int myl = lvl_s[tid];
  int ml = myl;
  #pragma unroll
  for (int m = 1; m < 64; m <<= 1) ml = max(ml, __shfl_xor(ml, m, 64));
  if (lane == 0) atomicMax(&lmax_s, ml);
  atomicAdd(&cnt_s[myl], 1);
  __syncthreads();
  const int Lmax = lmax_s;
  if (tid == 0) {
    int acc = 0;
    for (int L = 0; L <= Lmax; ++L) { offs_s[L] = acc; acc += cnt_s[L]; }
    offs_s[Lmax + 1] = acc;
  }
  __syncthreads();
  {
    int pos = offs_s[myl] + atomicAdd(&cnt2_s[myl], 1);
    ord_s[pos] = tid;
  }
  __syncthreads();

  const int m16  = lane & 15;
  const int quad = lane >> 4;
  const unsigned short* Wq = Wp + (size_t)(w * 4) * 512 + (size_t)lane * 8;

  float bias[4];
  #pragma unroll
  for (int nt = 0; nt < 4; ++nt) bias[nt] = b_ih[(w * 4 + nt) * 16 + m16];

  // ---- level loop ----
  for (int L = 0; L <= Lmax; ++L) {
    const int start = offs_s[L], end = offs_s[L + 1];
    for (int m0 = start; m0 < end; m0 += 32) {
      const int nodes = min(32, end - m0);
      if (nodes <= 8)
        do_pass<1>(A_s, ord_s, li_s, ri_s, val_s, m0, nodes, Hb, Wq, W_ih, bias, tid, w, lane, m16, quad);
      else if (nodes <= 16)
        do_pass<2>(A_s, ord_s, li_s, ri_s, val_s, m0, nodes, Hb, Wq, W_ih, bias, tid, w, lane, m16, quad);
      else
        do_pass<4>(A_s, ord_s, li_s, ri_s, val_s, m0, nodes, Hb, Wq, W_ih, bias, tid, w, lane, m16, quad);
    }
  }

  // ---- logits + log_softmax ----
  hroot_s[tid] = bf2f(Hb[(size_t)(NNODE - 1) * HIDD + tid]);
  __syncthreads();
  {
    const int j = tid >> 3, part = tid & 7;
    if (j < OUTD) {
      float p = 0.f;
      const int k0 = part * 64;
      for (int k = k0; k < k0 + 64; ++k)
        p += hroot_s[k] * W_o[(size_t)k * OUTD + j];
      red_s[j][part] = p;
    }
  }
  __syncthreads();
  if (tid < OUTD) {
    float s = b_o[tid];
    #pragma unroll
    for (int p = 0; p < 8; ++p) s += red_s[tid][p];
    logit_s[tid] = s;
  }
  __syncthreads();
  if (w == 0) {
    float x = (lane < OUTD) ? logit_s[lane] : -1e30f;
    float mx = x;
    #pragma unroll
    for (int m = 1; m < 64; m <<= 1) mx = fmaxf(mx, __shfl_xor(mx, m, 64));
    float ex = (lane < OUTD) ? __expf(x - mx) : 0.f;
    float sm = ex;
    #pragma unroll
    for (int m = 1; m < 64; m <<= 1) sm += __shfl_xor(sm, m, 64);
    float ls = logf(sm);
    if (lane < OUTD) out[b * OUTD + lane] = x - mx - ls;
  }
}

extern "C" void kernel_launch(void* const* d_in, const int* in_sizes, int n_in,
                              void* d_out, int out_size, void* d_ws, size_t ws_size,
                              hipStream_t stream) {
  const int*   left   = (const int*)  d_in[0];
  const int*   right  = (const int*)  d_in[1];
  const int*   values = (const int*)  d_in[2];
  const float* W_ih   = (const float*)d_in[3];
  const float* b_ih   = (const float*)d_in[4];
  const float* W_o    = (const float*)d_in[5];
  const float* b_o    = (const float*)d_in[6];
  float* out = (float*)d_out;

  unsigned short* Wp   = (unsigned short*)d_ws;
  unsigned short* Hbuf = (unsigned short*)((char*)d_ws + 512 * 1024);

  pack_wh<<<1024, 256, 0, stream>>>(W_ih, Wp);
  tree_rnn<<<BATCH, 512, 0, stream>>>(left, right, values, W_ih, b_ih, W_o, b_o,
                                      Wp, Hbuf, out);
}